// Round 14
// baseline (694.908 us; speedup 1.0000x reference)
//
#include <hip/hip_runtime.h>
#include <math.h>

#define BB 8
#define NN 2048
#define HID 768
#define NHEADS 4
#define VOCAB 15
#define ALPHA 0.2f
#define NEGV -9e15f
#define MTOT (BB * NN)  // 16384

using short4v = __attribute__((ext_vector_type(4))) short;
using short8v = __attribute__((ext_vector_type(8))) short;
using f32x4 = __attribute__((ext_vector_type(4))) float;

__device__ __forceinline__ short f2bf(float f) {
  union { float f; unsigned u; } x;
  x.f = f;
  unsigned r = x.u + 0x7fffu + ((x.u >> 16) & 1u);
  return (short)(r >> 16);
}

__device__ __forceinline__ void cp16(const void* g, void* l) {
  __builtin_amdgcn_global_load_lds(
      (const __attribute__((address_space(1))) unsigned int*)g,
      (__attribute__((address_space(3))) unsigned int*)l, 16, 0, 0);
}

// ---------------------------------------------------------------------------
// Mega-setup: [0,PACK_B) adjacency bit-pack (1024 elems/block);
// [+ZERO_B) zero {Wh1,Wh2,TW}; [+NFM_B) per-batch vocab bitmasks;
// [+TRAN_B) W_out transpose; [+TW_B) TW partial GEMM (independent of rest).
// ---------------------------------------------------------------------------
#define PACK_B 32768
#define ZERO_B 308
#define NFM_B 64
#define TRAN_B 2304  // 96 x 24 tiles of 32x32
#define TW_B 192     // 12 col-chunks x 16 k-chunks
__global__ __launch_bounds__(256) void setup_kernel(
    const int* __restrict__ adj, unsigned long long* __restrict__ packed,
    float* __restrict__ zbase, const int* __restrict__ nf,
    unsigned long long* __restrict__ nfm, const float* __restrict__ W_out,
    short* __restrict__ Wt_o, const float* __restrict__ table,
    const float* __restrict__ W_heads, float* __restrict__ TW) {
  const int bid = blockIdx.x;
  const int tid = threadIdx.x;
  if (bid < PACK_B) {
    // 1024 consecutive adj values per block, 4 ballot rounds
    long base = (long)bid * 1024;
#pragma unroll
    for (int r = 0; r < 4; ++r) {
      long idx = base + r * 256 + tid;
      unsigned long long m = __ballot(adj[idx] > 0);
      if ((tid & 63) == 0) packed[idx >> 6] = m;
    }
  } else if (bid < PACK_B + ZERO_B) {
    zbase[(bid - PACK_B) * 256 + tid] = 0.f;
  } else if (bid < PACK_B + ZERO_B + NFM_B) {
    // vocab bitmasks: block c of batch b handles j in [c*256, c*256+256)
    int r = bid - PACK_B - ZERO_B;  // 0..63
    int b = r >> 3, c = r & 7;
    int w = tid >> 6;  // wave 0..3
    int j = c * 256 + tid;
    int nfv = nf[b * NN + j];
#pragma unroll
    for (int v = 0; v < VOCAB; ++v) {
      unsigned long long m = __ballot(nfv == v);
      if ((tid & 63) == 0) nfm[((long)b * VOCAB + v) * 32 + c * 4 + w] = m;
    }
  } else if (bid < PACK_B + ZERO_B + NFM_B + TRAN_B) {
    // W_out transpose (3072x768 -> bf16 768x3072)
    __shared__ float t[32][33];
    int r2 = bid - PACK_B - ZERO_B - NFM_B;
    const int K = NHEADS * HID, N = HID;
    int k0 = (r2 % 96) * 32, n0 = (r2 / 96) * 32;
    int tx = tid & 31, ty = tid >> 5;
#pragma unroll
    for (int i = 0; i < 32; i += 8)
      t[ty + i][tx] = W_out[(long)(k0 + ty + i) * N + n0 + tx];
    __syncthreads();
#pragma unroll
    for (int i = 0; i < 32; i += 8)
      Wt_o[(long)(n0 + ty + i) * K + k0 + tx] = f2bf(t[tx][ty + i]);
  } else {
    // TW[v][c] partial: col-chunk cx (256 cols), k-chunk ky (48 k)
    // NOTE: atomicAdd into TW, which the ZERO range of THIS SAME launch
    // zeroes -- different blocks, no ordering! So TW must be zeroed by the
    // previous call's... NOT SAFE. Instead: TW accumulators start from the
    // first k-chunk writing (ky==0 stores, others atomicAdd after). We avoid
    // the race by having ky==0 do a plain store only after computing, and
    // other ky atomicAdd -- still racy vs ky==0. Use a separate zero-free
    // scheme: each (cx) column is owned by 16 ky blocks; we instead write
    // per-ky partials to disjoint slots and let tw12/hcat sum? Too complex.
    // SAFE SCHEME: TW zeroing was moved OUT of zbase (see host: zbase only
    // covers Wh1/Wh2), and TW here is accumulated via atomicAdd onto a
    // region zeroed by the PREVIOUS kernel_launch? Not valid either.
    // => Simplest safe: ky blocks atomicAdd into TW, and TW is zeroed by
    // the ZERO range of this launch. To break the race, ZERO covers only
    // Wh1/Wh2 (512 KB -> 128 blocks) and TW zeroing is fused HERE: each
    // (cx, ky=0) block first stores its own partial (overwrite), and the
    // 15 other ky blocks spin... no spinning allowed.
    __shared__ float tbl[VOCAB][48];
    int r3 = bid - PACK_B - ZERO_B - NFM_B - TRAN_B;  // 0..191
    const int cx = r3 % 12, ky = r3 / 12;
    const int c = cx * 256 + tid;
    const int h = (cx * 256) / HID;
    const int n = c - h * HID;
    const int k0 = ky * 48;
    for (int idx = tid; idx < VOCAB * 48; idx += 256)
      tbl[idx / 48][idx % 48] = table[(idx / 48) * HID + k0 + idx % 48];
    __syncthreads();
    float acc[VOCAB];
#pragma unroll
    for (int v = 0; v < VOCAB; ++v) acc[v] = 0.f;
    const float* wp = W_heads + (long)h * HID * HID + (long)k0 * HID + n;
#pragma unroll 8
    for (int kk = 0; kk < 48; ++kk) {
      float w = wp[(long)kk * HID];
#pragma unroll
      for (int v = 0; v < VOCAB; ++v) acc[v] = fmaf(tbl[v][kk], w, acc[v]);
    }
    // TWp: per-ky disjoint partial buffer [ky][v][3072] -- no race, no zero
#pragma unroll
    for (int v = 0; v < VOCAB; ++v)
      TW[((long)ky * VOCAB + v) * (NHEADS * HID) + c] = acc[v];
  }
}

// ---------------------------------------------------------------------------
// Reduce the 16 TW partials -> TW final, and compute TW1/TW2 dots.
// grid: 12 blocks for TW reduce (256 cols each) + 60 for the a-dots.
// TW reduce must precede tw12-dots... SAME-LAUNCH dependency again — so this
// kernel only reduces; tw12 stays separate. grid 12 blocks.
// ---------------------------------------------------------------------------
__global__ __launch_bounds__(256) void tw_reduce_kernel(
    const float* __restrict__ TWp, float* __restrict__ TW) {
  const int c = blockIdx.x * 256 + threadIdx.x;  // 0..3071
#pragma unroll
  for (int v = 0; v < VOCAB; ++v) {
    float s = 0.f;
#pragma unroll
    for (int ky = 0; ky < 16; ++ky)
      s += TWp[((long)ky * VOCAB + v) * (NHEADS * HID) + c];
    TW[v * (NHEADS * HID) + c] = s;
  }
}

// ---------------------------------------------------------------------------
// TW1[h][v] = TW[v][h*HID:] . a1_h ; TW2 likewise. grid 60 blocks.
// ---------------------------------------------------------------------------
__global__ __launch_bounds__(256) void tw12_kernel(
    const float* __restrict__ TW, const float* __restrict__ a_heads,
    float* __restrict__ TW1, float* __restrict__ TW2) {
  int h = blockIdx.x / VOCAB, v = blockIdx.x % VOCAB;
  const float* twr = TW + v * (NHEADS * HID) + h * HID;
  const float* a1 = a_heads + h * 2 * HID;
  float s1 = 0.f, s2 = 0.f;
  for (int n = threadIdx.x; n < HID; n += 256) {
    float t = twr[n];
    s1 = fmaf(t, a1[n], s1);
    s2 = fmaf(t, a1[HID + n], s2);
  }
  __shared__ float r1[256], r2[256];
  r1[threadIdx.x] = s1;
  r2[threadIdx.x] = s2;
  __syncthreads();
  for (int s = 128; s > 0; s >>= 1) {
    if (threadIdx.x < s) {
      r1[threadIdx.x] += r1[threadIdx.x + s];
      r2[threadIdx.x] += r2[threadIdx.x + s];
    }
    __syncthreads();
  }
  if (threadIdx.x == 0) {
    TW1[h * VOCAB + v] = r1[0];
    TW2[h * VOCAB + v] = r2[0];
  }
}

// ---------------------------------------------------------------------------
// P16 via popcount: one wave per row; 15-value softmax for all 4 heads.
// ---------------------------------------------------------------------------
__global__ __launch_bounds__(256) void p16_kernel(
    const int* __restrict__ nf, const unsigned* __restrict__ padj32,
    const unsigned* __restrict__ nfm32, const float* __restrict__ TW1,
    const float* __restrict__ TW2, float* __restrict__ P16) {
  const int t = threadIdx.x;
  const int wv = t >> 6;
  const int lane = t & 63;
  const int rowm = blockIdx.x * 4 + wv;
  const int b = rowm >> 11;
  __shared__ float cnts[4][16];

  unsigned a = padj32[(long)rowm * 64 + lane];
  const unsigned* nb = nfm32 + (long)b * VOCAB * 64 + lane;
  int cnt[VOCAB];
#pragma unroll
  for (int v = 0; v < VOCAB; ++v) cnt[v] = __popc(a & nb[v * 64]);
#pragma unroll
  for (int off = 1; off < 64; off <<= 1)
#pragma unroll
    for (int v = 0; v < VOCAB; ++v) cnt[v] += __shfl_xor(cnt[v], off);
  int cntsum = 0;
#pragma unroll
  for (int v = 0; v < VOCAB; ++v) cntsum += cnt[v];
  const bool use_full = (cntsum == 0);  // wave-uniform
  if (use_full) {
#pragma unroll
    for (int v = 0; v < VOCAB; ++v) cnt[v] = __popc(nb[v * 64]);
#pragma unroll
    for (int off = 1; off < 64; off <<= 1)
#pragma unroll
      for (int v = 0; v < VOCAB; ++v) cnt[v] += __shfl_xor(cnt[v], off);
  }
  if (lane < 16) cnts[wv][lane] = (lane < VOCAB) ? (float)cnt[lane] : 0.f;
  __syncthreads();

  const int h = lane >> 4;
  const int v = lane & 15;
  const int nfi = nf[b * NN + (rowm & 2047)];
  float cvf = cnts[wv][v];
  bool valid = (v < VOCAB) && (cvf > 0.f);
  float logit = 0.f;
  if (!use_full) {
    float s = TW1[h * VOCAB + nfi] + ((v < VOCAB) ? TW2[h * VOCAB + v] : 0.f);
    logit = s > 0.f ? s : ALPHA * s;
  }
  float mv = valid ? logit : -INFINITY;
#pragma unroll
  for (int off = 1; off < 16; off <<= 1) mv = fmaxf(mv, __shfl_xor(mv, off));
  float pv = valid ? cvf * __expf(logit - mv) : 0.f;
  float sum = pv;
#pragma unroll
  for (int off = 1; off < 16; off <<= 1) sum += __shfl_xor(sum, off);
  if (v < VOCAB) P16[((long)h * 16384 + rowm) * 16 + v] = pv / sum;
}

// ---------------------------------------------------------------------------
// hcat[r][h*HID+colh] = ELU( sum_v P16[h][r][v] * TW[v][h*HID+colh] ) -> bf16
// 16B stores: each thread 8 cols x 16 rows.
// ---------------------------------------------------------------------------
__global__ __launch_bounds__(256) void hcat_expand(
    const float* __restrict__ TW, const float* __restrict__ P16,
    short* __restrict__ hcat) {
  __shared__ float twl[VOCAB * 128];
  __shared__ float pl[128 * 16];
  const int c0 = blockIdx.x * 128;
  const int r0 = blockIdx.y * 128;
  const int h = c0 / HID;
  const int t = threadIdx.x;
  for (int idx = t; idx < VOCAB * 128; idx += 256)
    twl[idx] = TW[(idx / 128) * (NHEADS * HID) + c0 + (idx & 127)];
  for (int idx = t; idx < 128 * 16; idx += 256)
    pl[idx] = P16[((long)h * 16384 + r0 + (idx >> 4)) * 16 + (idx & 15)];
  __syncthreads();
  const int clb = (t & 15) * 8;
  const int rlb = (t >> 4) * 8;
#pragma unroll
  for (int rr = 0; rr < 8; ++rr) {
    int rl = rlb + rr;
    short8v o;
#pragma unroll
    for (int cc = 0; cc < 8; ++cc) {
      float s = 0.f;
#pragma unroll
      for (int vv = 0; vv < VOCAB; ++vv)
        s = fmaf(pl[rl * 16 + vv], twl[vv * 128 + clb + cc], s);
      s = s > 0.f ? s : (__expf(s) - 1.f);
      o[cc] = f2bf(s);
    }
    *(short8v*)(hcat + (long)(r0 + rl) * (NHEADS * HID) + c0 + clb) = o;
  }
}

// ---------------------------------------------------------------------------
// bf16 MFMA GEMM, 128x128 tile, BK=32, XCD swizzle, LDS-repacked epilogues.
// MODE 0: Ct bf16 [bb][colh][row] via LDS + fused a-dot atomics (layer 2).
// MODE 3: fused ELU + mean-pool: atomicAdd Cf[z*HID + col].
// ---------------------------------------------------------------------------
template <int MODE>
__global__ __launch_bounds__(256, 4) void mfma_gemm(
    const short* __restrict__ A, const short* __restrict__ B,
    int K, int lda, int ldb, long sA, long sB,
    float* __restrict__ Cf, short* __restrict__ Ct,
    const float* __restrict__ a_vec, float* __restrict__ Wh1g,
    float* __restrict__ Wh2g) {
  __shared__ short smem[8704];  // As 4096 + Bs 4096; reused as ctile
  short* As = smem;
  short* Bs = smem + 4096;

  const int gx = gridDim.x, gy = gridDim.y;
  int lin = blockIdx.x + gx * (blockIdx.y + gy * blockIdx.z);
  const int per = (gx * gy * gridDim.z) >> 3;
  int work = (lin & 7) * per + (lin >> 3);
  const int bx = work % gx;
  int tmp = work / gx;
  const int by = tmp % gy;
  const int z = tmp / gy;

  A += (long)z * sA;
  B += (long)z * sB;

  const int tid = threadIdx.x;
  const int m0 = by * 128;
  const int n0 = bx * 128;

  const int lane = tid & 63;
  const int wid = tid >> 6;
  const int wm = (wid & 1) * 64;
  const int wn = (wid >> 1) * 64;
  const int l15 = lane & 15;
  const int quad = lane >> 4;
  const int cp = quad ^ ((l15 >> 1) & 3);

  f32x4 acc[4][4];
#pragma unroll
  for (int i = 0; i < 4; ++i)
#pragma unroll
    for (int j = 0; j < 4; ++j) acc[i][j] = (f32x4){0.f, 0.f, 0.f, 0.f};

  for (int k0 = 0; k0 < K; k0 += 32) {
#pragma unroll
    for (int it = 0; it < 2; ++it) {
      int lin2 = it * 256 + tid;
      int r = lin2 >> 2;
      int p = lin2 & 3;
      int kc = p ^ ((r >> 1) & 3);
      cp16(A + (long)(m0 + r) * lda + k0 + kc * 8, &As[lin2 * 8]);
    }
#pragma unroll
    for (int it = 0; it < 2; ++it) {
      int lin2 = it * 256 + tid;
      int r = lin2 >> 2;
      int p = lin2 & 3;
      int kc = p ^ ((r >> 1) & 3);
      cp16(B + (long)(n0 + r) * ldb + k0 + kc * 8, &Bs[lin2 * 8]);
    }
    __syncthreads();

    short8v af[4], bfr[4];
#pragma unroll
    for (int i = 0; i < 4; ++i)
      af[i] = *(const short8v*)(As + (wm + i * 16 + l15) * 32 + cp * 8);
#pragma unroll
    for (int j = 0; j < 4; ++j)
      bfr[j] = *(const short8v*)(Bs + (wn + j * 16 + l15) * 32 + cp * 8);
#pragma unroll
    for (int i = 0; i < 4; ++i)
#pragma unroll
      for (int j = 0; j < 4; ++j)
        acc[i][j] = __builtin_amdgcn_mfma_f32_16x16x32_bf16(af[i], bfr[j],
                                                            acc[i][j], 0, 0, 0);
    __syncthreads();
  }

  // ---- epilogues (C/D layout: col=lane&15 group, row=quad*4+reg) ----
  if constexpr (MODE == 3) {
#pragma unroll
    for (int j = 0; j < 4; ++j) {
      int col = n0 + wn + j * 16 + l15;
      float s = 0.f;
#pragma unroll
      for (int i = 0; i < 4; ++i)
#pragma unroll
        for (int reg = 0; reg < 4; ++reg) {
          float v = acc[i][j][reg];
          s += v > 0.f ? v : (__expf(v) - 1.f);
        }
      s += __shfl_xor(s, 16);
      s += __shfl_xor(s, 32);
      if (quad == 0) atomicAdd(Cf + (long)z * HID + col, s * (1.0f / NN));
    }
  } else {  // MODE 0: a-dot + transposed Ct via LDS [col][row] (stride 136)
    float a1v[4], a2v[4];
#pragma unroll
    for (int j = 0; j < 4; ++j) {
      int colh = n0 + wn + j * 16 + l15;  // single-head output (N=768)
      a1v[j] = a_vec[colh];
      a2v[j] = a_vec[HID + colh];
    }
#pragma unroll
    for (int i = 0; i < 4; ++i) {
      int rb = m0 + wm + i * 16 + quad * 4;
#pragma unroll
      for (int reg = 0; reg < 4; ++reg) {
        float s1 = 0.f, s2 = 0.f;
#pragma unroll
        for (int j = 0; j < 4; ++j) {
          s1 = fmaf(acc[i][j][reg], a1v[j], s1);
          s2 = fmaf(acc[i][j][reg], a2v[j], s2);
        }
#pragma unroll
        for (int off = 1; off < 16; off <<= 1) {
          s1 += __shfl_xor(s1, off);
          s2 += __shfl_xor(s2, off);
        }
        if (l15 == 0) {
          atomicAdd(Wh1g + rb + reg, s1);
          atomicAdd(Wh2g + rb + reg, s2);
        }
      }
    }
    const int bb = m0 >> 11;
    const int ml0 = m0 & 2047;
#pragma unroll
    for (int p = 0; p < 2; ++p) {
      if (wn == p * 64) {
#pragma unroll
        for (int j = 0; j < 4; ++j) {
          int col_l = j * 16 + l15;
#pragma unroll
          for (int i = 0; i < 4; ++i) {
            int row_l = wm + i * 16 + quad * 4;
            short4v pk;
#pragma unroll
            for (int reg = 0; reg < 4; ++reg) pk[reg] = f2bf(acc[i][j][reg]);
            *(short4v*)(smem + col_l * 136 + row_l) = pk;
          }
        }
      }
      __syncthreads();
#pragma unroll
      for (int it = 0; it < 4; ++it) {
        int idx = it * 256 + tid;
        int col_l = idx >> 4;
        int ch = idx & 15;
        short8v ld = *(const short8v*)(smem + col_l * 136 + ch * 8);
        int colh = n0 + p * 64 + col_l;
        *(short8v*)(Ct + ((long)bb * HID + colh) * NN + ml0 + ch * 8) = ld;
      }
      __syncthreads();
    }
  }
}

// ---------------------------------------------------------------------------
// Layer-2 row softmax (materializing, bf16 att). grid 16384. Blocks [0,zn)
// also zero zA (final output accumulator; write-disjoint from reads).
// ---------------------------------------------------------------------------
__global__ __launch_bounds__(256) void attn_softmax_kernel(
    const float* __restrict__ Wh1, const float* __restrict__ Wh2,
    const unsigned long long* __restrict__ packed, short* __restrict__ att,
    float* __restrict__ zA, int zn) {
  int row = blockIdx.x;
  if (row < zn) zA[row * 256 + threadIdx.x] = 0.f;
  int b = row >> 11;
  const unsigned char* bits = (const unsigned char*)(packed + (long)row * 32);
  const float* wh2b = Wh2 + b * NN;
  const int t = threadIdx.x;
  const int lane = t & 63;
  const int wv = t >> 6;

  unsigned m8 = bits[t];
  float wh1 = Wh1[row];
  float4 wa = ((const float4*)(wh2b + t * 8))[0];
  float4 wb = ((const float4*)(wh2b + t * 8))[1];
  float v[8] = {wa.x, wa.y, wa.z, wa.w, wb.x, wb.y, wb.z, wb.w};

  float lmax = -INFINITY;
#pragma unroll
  for (int k = 0; k < 8; ++k) {
    float s = wh1 + v[k];
    s = s > 0.f ? s : ALPHA * s;
    s = ((m8 >> k) & 1u) ? s : NEGV;
    v[k] = s;
    lmax = fmaxf(lmax, s);
  }

  __shared__ float redm[4], reds[4];
#pragma unroll
  for (int off = 32; off > 0; off >>= 1) lmax = fmaxf(lmax, __shfl_xor(lmax, off));
  if (lane == 0) redm[wv] = lmax;
  __syncthreads();
  float m = fmaxf(fmaxf(redm[0], redm[1]), fmaxf(redm[2], redm[3]));

  float lsum = 0.f;
#pragma unroll
  for (int k = 0; k < 8; ++k) {
    float p = __expf(v[k] - m);
    v[k] = p;
    lsum += p;
  }
#pragma unroll
  for (int off = 32; off > 0; off >>= 1) lsum += __shfl_xor(lsum, off);
  if (lane == 0) reds[wv] = lsum;
  __syncthreads();
  float inv = 1.f / (reds[0] + reds[1] + reds[2] + reds[3]);

  short8v o;
#pragma unroll
  for (int k = 0; k < 8; ++k) o[k] = f2bf(v[k] * inv);
  *(short8v*)(att + (long)row * NN + t * 8) = o;
}

// ---------------------------------------------------------------------------
extern "C" void kernel_launch(void* const* d_in, const int* in_sizes, int n_in,
                              void* d_out, int out_size, void* d_ws,
                              size_t ws_size, hipStream_t stream) {
  const int* node_feats = (const int*)d_in[0];
  const int* adjs = (const int*)d_in[1];
  const float* embed_table = (const float*)d_in[2];
  const float* W_heads = (const float*)d_in[3];
  const float* a_heads = (const float*)d_in[4];
  const float* W_out = (const float*)d_in[5];
  const float* a_out = (const float*)d_in[6];
  float* out = (float*)d_out;

  // workspace layout (~215 MB)
  char* p = (char*)d_ws;
  short* Wt_o = (short*)p;  p += (size_t)HID * (NHEADS * HID) * 2;       // 4.7 MB
  short* Wh_t = (short*)p;  p += (size_t)BB * HID * NN * 2;              // 25 MB
  short* att2 = (short*)p;  p += (size_t)BB * NN * NN * 2;               // 67 MB
  short* hcat = (short*)p;  p += (size_t)MTOT * NHEADS * HID * 2;        // 100 MB
  unsigned long long* padj = (unsigned long long*)p;
  p += (size_t)BB * NN * NN / 8;                                         // 4.2 MB
  float* P16 = (float*)p;   p += (size_t)NHEADS * 16384 * 16 * 4;        // 4 MB
  // zero region: Wh1 (16384) + Wh2 (16384) + pad to 308*256 floats
  float* Wh1 = (float*)p;   p += (size_t)16384 * 4;
  float* Wh2 = (float*)p;   p += (size_t)16384 * 4;
  p += (size_t)(ZERO_B * 256 - 2 * 16384) * 4;  // padding covered by ZERO
  float* TWp = (float*)p;   p += (size_t)16 * VOCAB * NHEADS * HID * 4;  // 2.9 MB
  float* TW = (float*)p;    p += (size_t)VOCAB * NHEADS * HID * 4;
  float* TW1 = (float*)p;   p += (size_t)NHEADS * VOCAB * 4;
  float* TW2 = (float*)p;   p += (size_t)NHEADS * VOCAB * 4;
  unsigned long long* nfm = (unsigned long long*)p;
  p += (size_t)BB * VOCAB * 32 * 8;                                      // 30 KB
  if ((size_t)(p - (char*)d_ws) > ws_size) return;

  // 0) mega-setup: adj pack + zeros + vocab masks + W_out transpose + TW
  //    partials (per-ky disjoint slots, no zero-init dependency)
  setup_kernel<<<PACK_B + ZERO_B + NFM_B + TRAN_B + TW_B, 256, 0, stream>>>(
      adjs, padj, Wh1, node_feats, nfm, W_out, Wt_o, embed_table, W_heads,
      TWp);

  // 1) layer 1 via rank-15 structure: TW reduce, a-dots, popcount-P16, expand
  tw_reduce_kernel<<<12, 256, 0, stream>>>(TWp, TW);
  tw12_kernel<<<NHEADS * VOCAB, 256, 0, stream>>>(TW, a_heads, TW1, TW2);
  p16_kernel<<<16384 / 4, 256, 0, stream>>>(
      node_feats, (const unsigned*)padj, (const unsigned*)nfm, TW1, TW2, P16);
  hcat_expand<<<dim3(24, 128), 256, 0, stream>>>(TW, P16, hcat);

  // 2) output GAT layer (full-rank): proj2 -> Wh_t + Wh1/Wh2 atomics
  mfma_gemm<0><<<dim3(HID / 128, MTOT / 128, 1), 256, 0, stream>>>(
      hcat, Wt_o, NHEADS * HID, NHEADS * HID, NHEADS * HID, 0, 0,
      nullptr, Wh_t, a_out, Wh1, Wh2);
  attn_softmax_kernel<<<MTOT, 256, 0, stream>>>(Wh1, Wh2, padj, att2, out, 24);
  mfma_gemm<3><<<dim3(HID / 128, NN / 128, BB), 256, 0, stream>>>(
      att2, Wh_t, NN, NN, NN, (long)NN * NN, (long)HID * NN,
      out, nullptr, nullptr, nullptr, nullptr);
}

// Round 15
// 538.756 us; speedup vs baseline: 1.2898x; 1.2898x over previous
//
#include <hip/hip_runtime.h>
#include <math.h>

#define BB 8
#define NN 2048
#define HID 768
#define NHEADS 4
#define VOCAB 15
#define ALPHA 0.2f
#define NEGV -9e15f
#define MTOT (BB * NN)  // 16384

using short4v = __attribute__((ext_vector_type(4))) short;
using short8v = __attribute__((ext_vector_type(8))) short;
using f32x4 = __attribute__((ext_vector_type(4))) float;

__device__ __forceinline__ short f2bf(float f) {
  union { float f; unsigned u; } x;
  x.f = f;
  unsigned r = x.u + 0x7fffu + ((x.u >> 16) & 1u);
  return (short)(r >> 16);
}

__device__ __forceinline__ void cp16(const void* g, void* l) {
  __builtin_amdgcn_global_load_lds(
      (const __attribute__((address_space(1))) unsigned int*)g,
      (__attribute__((address_space(3))) unsigned int*)l, 16, 0, 0);
}

// ---------------------------------------------------------------------------
// Mega-setup: [0,PACK_B) adjacency bit-pack (1024 elems/block);
// [+ZERO_B) zero {Wh1,Wh2,pad}; [+NFM_B) per-batch vocab bitmasks;
// [+TRAN_B) W_out transpose; [+TW_B) TW partials (per-ky disjoint slots).
// ---------------------------------------------------------------------------
#define PACK_B 32768
#define ZERO_B 308
#define NFM_B 64
#define TRAN_B 2304  // 96 x 24 tiles of 32x32
#define TW_B 192     // 12 col-chunks x 16 k-chunks
__global__ __launch_bounds__(256) void setup_kernel(
    const int* __restrict__ adj, unsigned long long* __restrict__ packed,
    float* __restrict__ zbase, const int* __restrict__ nf,
    unsigned long long* __restrict__ nfm, const float* __restrict__ W_out,
    short* __restrict__ Wt_o, const float* __restrict__ table,
    const float* __restrict__ W_heads, float* __restrict__ TWp) {
  const int bid = blockIdx.x;
  const int tid = threadIdx.x;
  if (bid < PACK_B) {
    long base = (long)bid * 1024;
#pragma unroll
    for (int r = 0; r < 4; ++r) {
      long idx = base + r * 256 + tid;
      unsigned long long m = __ballot(adj[idx] > 0);
      if ((tid & 63) == 0) packed[idx >> 6] = m;
    }
  } else if (bid < PACK_B + ZERO_B) {
    zbase[(bid - PACK_B) * 256 + tid] = 0.f;
  } else if (bid < PACK_B + ZERO_B + NFM_B) {
    int r = bid - PACK_B - ZERO_B;  // 0..63
    int b = r >> 3, c = r & 7;
    int w = tid >> 6;
    int j = c * 256 + tid;
    int nfv = nf[b * NN + j];
#pragma unroll
    for (int v = 0; v < VOCAB; ++v) {
      unsigned long long m = __ballot(nfv == v);
      if ((tid & 63) == 0) nfm[((long)b * VOCAB + v) * 32 + c * 4 + w] = m;
    }
  } else if (bid < PACK_B + ZERO_B + NFM_B + TRAN_B) {
    // W_out transpose (3072x768 -> bf16 768x3072)
    __shared__ float t[32][33];
    int r2 = bid - PACK_B - ZERO_B - NFM_B;
    const int K = NHEADS * HID, N = HID;
    int k0 = (r2 % 96) * 32, n0 = (r2 / 96) * 32;
    int tx = tid & 31, ty = tid >> 5;
#pragma unroll
    for (int i = 0; i < 32; i += 8)
      t[ty + i][tx] = W_out[(long)(k0 + ty + i) * N + n0 + tx];
    __syncthreads();
#pragma unroll
    for (int i = 0; i < 32; i += 8)
      Wt_o[(long)(n0 + ty + i) * K + k0 + tx] = f2bf(t[tx][ty + i]);
  } else {
    // TW partial: col-chunk cx (256 cols), k-chunk ky (48 k) -> disjoint slot
    __shared__ float tbl[VOCAB][48];
    int r3 = bid - PACK_B - ZERO_B - NFM_B - TRAN_B;  // 0..191
    const int cx = r3 % 12, ky = r3 / 12;
    const int c = cx * 256 + tid;
    const int h = (cx * 256) / HID;
    const int n = c - h * HID;
    const int k0 = ky * 48;
    for (int idx = tid; idx < VOCAB * 48; idx += 256)
      tbl[idx / 48][idx % 48] = table[(idx / 48) * HID + k0 + idx % 48];
    __syncthreads();
    float acc[VOCAB];
#pragma unroll
    for (int v = 0; v < VOCAB; ++v) acc[v] = 0.f;
    const float* wp = W_heads + (long)h * HID * HID + (long)k0 * HID + n;
#pragma unroll 8
    for (int kk = 0; kk < 48; ++kk) {
      float w = wp[(long)kk * HID];
#pragma unroll
      for (int v = 0; v < VOCAB; ++v) acc[v] = fmaf(tbl[v][kk], w, acc[v]);
    }
#pragma unroll
    for (int v = 0; v < VOCAB; ++v)
      TWp[((long)ky * VOCAB + v) * (NHEADS * HID) + c] = acc[v];
  }
}

// ---------------------------------------------------------------------------
// Reduce the 16 TW partials -> TW final. grid 12 blocks.
// ---------------------------------------------------------------------------
__global__ __launch_bounds__(256) void tw_reduce_kernel(
    const float* __restrict__ TWp, float* __restrict__ TW) {
  const int c = blockIdx.x * 256 + threadIdx.x;  // 0..3071
#pragma unroll
  for (int v = 0; v < VOCAB; ++v) {
    float s = 0.f;
#pragma unroll
    for (int ky = 0; ky < 16; ++ky)
      s += TWp[((long)ky * VOCAB + v) * (NHEADS * HID) + c];
    TW[v * (NHEADS * HID) + c] = s;
  }
}

// ---------------------------------------------------------------------------
// TW1[h][v] = TW[v][h*HID:] . a1_h ; TW2 likewise. grid 60 blocks.
// ---------------------------------------------------------------------------
__global__ __launch_bounds__(256) void tw12_kernel(
    const float* __restrict__ TW, const float* __restrict__ a_heads,
    float* __restrict__ TW1, float* __restrict__ TW2) {
  int h = blockIdx.x / VOCAB, v = blockIdx.x % VOCAB;
  const float* twr = TW + v * (NHEADS * HID) + h * HID;
  const float* a1 = a_heads + h * 2 * HID;
  float s1 = 0.f, s2 = 0.f;
  for (int n = threadIdx.x; n < HID; n += 256) {
    float t = twr[n];
    s1 = fmaf(t, a1[n], s1);
    s2 = fmaf(t, a1[HID + n], s2);
  }
  __shared__ float r1[256], r2[256];
  r1[threadIdx.x] = s1;
  r2[threadIdx.x] = s2;
  __syncthreads();
  for (int s = 128; s > 0; s >>= 1) {
    if (threadIdx.x < s) {
      r1[threadIdx.x] += r1[threadIdx.x + s];
      r2[threadIdx.x] += r2[threadIdx.x + s];
    }
    __syncthreads();
  }
  if (threadIdx.x == 0) {
    TW1[h * VOCAB + v] = r1[0];
    TW2[h * VOCAB + v] = r2[0];
  }
}

// ---------------------------------------------------------------------------
// P16 via popcount: one wave per row; 15-value softmax for all 4 heads.
// ---------------------------------------------------------------------------
__global__ __launch_bounds__(256) void p16_kernel(
    const int* __restrict__ nf, const unsigned* __restrict__ padj32,
    const unsigned* __restrict__ nfm32, const float* __restrict__ TW1,
    const float* __restrict__ TW2, float* __restrict__ P16) {
  const int t = threadIdx.x;
  const int wv = t >> 6;
  const int lane = t & 63;
  const int rowm = blockIdx.x * 4 + wv;
  const int b = rowm >> 11;
  __shared__ float cnts[4][16];

  unsigned a = padj32[(long)rowm * 64 + lane];
  const unsigned* nb = nfm32 + (long)b * VOCAB * 64 + lane;
  int cnt[VOCAB];
#pragma unroll
  for (int v = 0; v < VOCAB; ++v) cnt[v] = __popc(a & nb[v * 64]);
#pragma unroll
  for (int off = 1; off < 64; off <<= 1)
#pragma unroll
    for (int v = 0; v < VOCAB; ++v) cnt[v] += __shfl_xor(cnt[v], off);
  int cntsum = 0;
#pragma unroll
  for (int v = 0; v < VOCAB; ++v) cntsum += cnt[v];
  const bool use_full = (cntsum == 0);  // wave-uniform
  if (use_full) {
#pragma unroll
    for (int v = 0; v < VOCAB; ++v) cnt[v] = __popc(nb[v * 64]);
#pragma unroll
    for (int off = 1; off < 64; off <<= 1)
#pragma unroll
      for (int v = 0; v < VOCAB; ++v) cnt[v] += __shfl_xor(cnt[v], off);
  }
  if (lane < 16) cnts[wv][lane] = (lane < VOCAB) ? (float)cnt[lane] : 0.f;
  __syncthreads();

  const int h = lane >> 4;
  const int v = lane & 15;
  const int nfi = nf[b * NN + (rowm & 2047)];
  float cvf = cnts[wv][v];
  bool valid = (v < VOCAB) && (cvf > 0.f);
  float logit = 0.f;
  if (!use_full) {
    float s = TW1[h * VOCAB + nfi] + ((v < VOCAB) ? TW2[h * VOCAB + v] : 0.f);
    logit = s > 0.f ? s : ALPHA * s;
  }
  float mv = valid ? logit : -INFINITY;
#pragma unroll
  for (int off = 1; off < 16; off <<= 1) mv = fmaxf(mv, __shfl_xor(mv, off));
  float pv = valid ? cvf * __expf(logit - mv) : 0.f;
  float sum = pv;
#pragma unroll
  for (int off = 1; off < 16; off <<= 1) sum += __shfl_xor(sum, off);
  if (v < VOCAB) P16[((long)h * 16384 + rowm) * 16 + v] = pv / sum;
}

// ---------------------------------------------------------------------------
// hcat[r][h*HID+colh] = ELU( sum_v P16[h][r][v] * TW[v][h*HID+colh] ) -> bf16
// ROUND-13 layout (reverted): 4 cols x 16 rows per thread, short4v stores.
// ---------------------------------------------------------------------------
__global__ __launch_bounds__(256) void hcat_expand(
    const float* __restrict__ TW, const float* __restrict__ P16,
    short* __restrict__ hcat) {
  __shared__ float twl[VOCAB * 128];
  __shared__ float pl[128 * 16];
  const int c0 = blockIdx.x * 128;
  const int r0 = blockIdx.y * 128;
  const int h = c0 / HID;
  const int t = threadIdx.x;
  for (int idx = t; idx < VOCAB * 128; idx += 256)
    twl[idx] = TW[(idx / 128) * (NHEADS * HID) + c0 + (idx & 127)];
  for (int idx = t; idx < 128 * 16; idx += 256)
    pl[idx] = P16[((long)h * 16384 + r0 + (idx >> 4)) * 16 + (idx & 15)];
  __syncthreads();
  const int clb = (t & 31) * 4;
  const int rlb = (t >> 5) * 16;
#pragma unroll 4
  for (int rr = 0; rr < 16; ++rr) {
    int rl = rlb + rr;
    short4v o;
#pragma unroll
    for (int cc = 0; cc < 4; ++cc) {
      float s = 0.f;
#pragma unroll
      for (int vv = 0; vv < VOCAB; ++vv)
        s = fmaf(pl[rl * 16 + vv], twl[vv * 128 + clb + cc], s);
      s = s > 0.f ? s : (__expf(s) - 1.f);
      o[cc] = f2bf(s);
    }
    *(short4v*)(hcat + (long)(r0 + rl) * (NHEADS * HID) + c0 + clb) = o;
  }
}

// ---------------------------------------------------------------------------
// bf16 MFMA GEMM, 128x128 tile, BK=32, XCD swizzle, LDS-repacked epilogues.
// MODE 0: Ct bf16 [bb][colh][row] via LDS + fused a-dot atomics (layer 2).
// MODE 3: fused ELU + mean-pool: atomicAdd Cf[z*HID + col].
// ---------------------------------------------------------------------------
template <int MODE>
__global__ __launch_bounds__(256, 4) void mfma_gemm(
    const short* __restrict__ A, const short* __restrict__ B,
    int K, int lda, int ldb, long sA, long sB,
    float* __restrict__ Cf, short* __restrict__ Ct,
    const float* __restrict__ a_vec, float* __restrict__ Wh1g,
    float* __restrict__ Wh2g) {
  __shared__ short smem[8704];  // As 4096 + Bs 4096; reused as ctile
  short* As = smem;
  short* Bs = smem + 4096;

  const int gx = gridDim.x, gy = gridDim.y;
  int lin = blockIdx.x + gx * (blockIdx.y + gy * blockIdx.z);
  const int per = (gx * gy * gridDim.z) >> 3;
  int work = (lin & 7) * per + (lin >> 3);
  const int bx = work % gx;
  int tmp = work / gx;
  const int by = tmp % gy;
  const int z = tmp / gy;

  A += (long)z * sA;
  B += (long)z * sB;

  const int tid = threadIdx.x;
  const int m0 = by * 128;
  const int n0 = bx * 128;

  const int lane = tid & 63;
  const int wid = tid >> 6;
  const int wm = (wid & 1) * 64;
  const int wn = (wid >> 1) * 64;
  const int l15 = lane & 15;
  const int quad = lane >> 4;
  const int cp = quad ^ ((l15 >> 1) & 3);

  f32x4 acc[4][4];
#pragma unroll
  for (int i = 0; i < 4; ++i)
#pragma unroll
    for (int j = 0; j < 4; ++j) acc[i][j] = (f32x4){0.f, 0.f, 0.f, 0.f};

  for (int k0 = 0; k0 < K; k0 += 32) {
#pragma unroll
    for (int it = 0; it < 2; ++it) {
      int lin2 = it * 256 + tid;
      int r = lin2 >> 2;
      int p = lin2 & 3;
      int kc = p ^ ((r >> 1) & 3);
      cp16(A + (long)(m0 + r) * lda + k0 + kc * 8, &As[lin2 * 8]);
    }
#pragma unroll
    for (int it = 0; it < 2; ++it) {
      int lin2 = it * 256 + tid;
      int r = lin2 >> 2;
      int p = lin2 & 3;
      int kc = p ^ ((r >> 1) & 3);
      cp16(B + (long)(n0 + r) * ldb + k0 + kc * 8, &Bs[lin2 * 8]);
    }
    __syncthreads();

    short8v af[4], bfr[4];
#pragma unroll
    for (int i = 0; i < 4; ++i)
      af[i] = *(const short8v*)(As + (wm + i * 16 + l15) * 32 + cp * 8);
#pragma unroll
    for (int j = 0; j < 4; ++j)
      bfr[j] = *(const short8v*)(Bs + (wn + j * 16 + l15) * 32 + cp * 8);
#pragma unroll
    for (int i = 0; i < 4; ++i)
#pragma unroll
      for (int j = 0; j < 4; ++j)
        acc[i][j] = __builtin_amdgcn_mfma_f32_16x16x32_bf16(af[i], bfr[j],
                                                            acc[i][j], 0, 0, 0);
    __syncthreads();
  }

  // ---- epilogues (C/D layout: col=lane&15 group, row=quad*4+reg) ----
  if constexpr (MODE == 3) {
#pragma unroll
    for (int j = 0; j < 4; ++j) {
      int col = n0 + wn + j * 16 + l15;
      float s = 0.f;
#pragma unroll
      for (int i = 0; i < 4; ++i)
#pragma unroll
        for (int reg = 0; reg < 4; ++reg) {
          float v = acc[i][j][reg];
          s += v > 0.f ? v : (__expf(v) - 1.f);
        }
      s += __shfl_xor(s, 16);
      s += __shfl_xor(s, 32);
      if (quad == 0) atomicAdd(Cf + (long)z * HID + col, s * (1.0f / NN));
    }
  } else {  // MODE 0: a-dot + transposed Ct via LDS [col][row] (stride 136)
    float a1v[4], a2v[4];
#pragma unroll
    for (int j = 0; j < 4; ++j) {
      int colh = n0 + wn + j * 16 + l15;  // single-head output (N=768)
      a1v[j] = a_vec[colh];
      a2v[j] = a_vec[HID + colh];
    }
#pragma unroll
    for (int i = 0; i < 4; ++i) {
      int rb = m0 + wm + i * 16 + quad * 4;
#pragma unroll
      for (int reg = 0; reg < 4; ++reg) {
        float s1 = 0.f, s2 = 0.f;
#pragma unroll
        for (int j = 0; j < 4; ++j) {
          s1 = fmaf(acc[i][j][reg], a1v[j], s1);
          s2 = fmaf(acc[i][j][reg], a2v[j], s2);
        }
#pragma unroll
        for (int off = 1; off < 16; off <<= 1) {
          s1 += __shfl_xor(s1, off);
          s2 += __shfl_xor(s2, off);
        }
        if (l15 == 0) {
          atomicAdd(Wh1g + rb + reg, s1);
          atomicAdd(Wh2g + rb + reg, s2);
        }
      }
    }
    const int bb = m0 >> 11;
    const int ml0 = m0 & 2047;
#pragma unroll
    for (int p = 0; p < 2; ++p) {
      if (wn == p * 64) {
#pragma unroll
        for (int j = 0; j < 4; ++j) {
          int col_l = j * 16 + l15;
#pragma unroll
          for (int i = 0; i < 4; ++i) {
            int row_l = wm + i * 16 + quad * 4;
            short4v pk;
#pragma unroll
            for (int reg = 0; reg < 4; ++reg) pk[reg] = f2bf(acc[i][j][reg]);
            *(short4v*)(smem + col_l * 136 + row_l) = pk;
          }
        }
      }
      __syncthreads();
#pragma unroll
      for (int it = 0; it < 4; ++it) {
        int idx = it * 256 + tid;
        int col_l = idx >> 4;
        int ch = idx & 15;
        short8v ld = *(const short8v*)(smem + col_l * 136 + ch * 8);
        int colh = n0 + p * 64 + col_l;
        *(short8v*)(Ct + ((long)bb * HID + colh) * NN + ml0 + ch * 8) = ld;
      }
      __syncthreads();
    }
  }
}

// ---------------------------------------------------------------------------
// Layer-2 row softmax (materializing, bf16 att). grid 16384. Blocks [0,zn)
// also zero zA (final output accumulator; write-disjoint from reads).
// ---------------------------------------------------------------------------
__global__ __launch_bounds__(256) void attn_softmax_kernel(
    const float* __restrict__ Wh1, const float* __restrict__ Wh2,
    const unsigned long long* __restrict__ packed, short* __restrict__ att,
    float* __restrict__ zA, int zn) {
  int row = blockIdx.x;
  if (row < zn) zA[row * 256 + threadIdx.x] = 0.f;
  int b = row >> 11;
  const unsigned char* bits = (const unsigned char*)(packed + (long)row * 32);
  const float* wh2b = Wh2 + b * NN;
  const int t = threadIdx.x;
  const int lane = t & 63;
  const int wv = t >> 6;

  unsigned m8 = bits[t];
  float wh1 = Wh1[row];
  float4 wa = ((const float4*)(wh2b + t * 8))[0];
  float4 wb = ((const float4*)(wh2b + t * 8))[1];
  float v[8] = {wa.x, wa.y, wa.z, wa.w, wb.x, wb.y, wb.z, wb.w};

  float lmax = -INFINITY;
#pragma unroll
  for (int k = 0; k < 8; ++k) {
    float s = wh1 + v[k];
    s = s > 0.f ? s : ALPHA * s;
    s = ((m8 >> k) & 1u) ? s : NEGV;
    v[k] = s;
    lmax = fmaxf(lmax, s);
  }

  __shared__ float redm[4], reds[4];
#pragma unroll
  for (int off = 32; off > 0; off >>= 1) lmax = fmaxf(lmax, __shfl_xor(lmax, off));
  if (lane == 0) redm[wv] = lmax;
  __syncthreads();
  float m = fmaxf(fmaxf(redm[0], redm[1]), fmaxf(redm[2], redm[3]));

  float lsum = 0.f;
#pragma unroll
  for (int k = 0; k < 8; ++k) {
    float p = __expf(v[k] - m);
    v[k] = p;
    lsum += p;
  }
#pragma unroll
  for (int off = 32; off > 0; off >>= 1) lsum += __shfl_xor(lsum, off);
  if (lane == 0) reds[wv] = lsum;
  __syncthreads();
  float inv = 1.f / (reds[0] + reds[1] + reds[2] + reds[3]);

  short8v o;
#pragma unroll
  for (int k = 0; k < 8; ++k) o[k] = f2bf(v[k] * inv);
  *(short8v*)(att + (long)row * NN + t * 8) = o;
}

// ---------------------------------------------------------------------------
extern "C" void kernel_launch(void* const* d_in, const int* in_sizes, int n_in,
                              void* d_out, int out_size, void* d_ws,
                              size_t ws_size, hipStream_t stream) {
  const int* node_feats = (const int*)d_in[0];
  const int* adjs = (const int*)d_in[1];
  const float* embed_table = (const float*)d_in[2];
  const float* W_heads = (const float*)d_in[3];
  const float* a_heads = (const float*)d_in[4];
  const float* W_out = (const float*)d_in[5];
  const float* a_out = (const float*)d_in[6];
  float* out = (float*)d_out;

  // workspace layout (~215 MB)
  char* p = (char*)d_ws;
  short* Wt_o = (short*)p;  p += (size_t)HID * (NHEADS * HID) * 2;       // 4.7 MB
  short* Wh_t = (short*)p;  p += (size_t)BB * HID * NN * 2;              // 25 MB
  short* att2 = (short*)p;  p += (size_t)BB * NN * NN * 2;               // 67 MB
  short* hcat = (short*)p;  p += (size_t)MTOT * NHEADS * HID * 2;        // 100 MB
  unsigned long long* padj = (unsigned long long*)p;
  p += (size_t)BB * NN * NN / 8;                                         // 4.2 MB
  float* P16 = (float*)p;   p += (size_t)NHEADS * 16384 * 16 * 4;        // 4 MB
  // zero region: Wh1 (16384) + Wh2 (16384) + pad to 308*256 floats
  float* Wh1 = (float*)p;   p += (size_t)16384 * 4;
  float* Wh2 = (float*)p;   p += (size_t)16384 * 4;
  p += (size_t)(ZERO_B * 256 - 2 * 16384) * 4;  // padding covered by ZERO
  float* TWp = (float*)p;   p += (size_t)16 * VOCAB * NHEADS * HID * 4;  // 2.9 MB
  float* TW = (float*)p;    p += (size_t)VOCAB * NHEADS * HID * 4;
  float* TW1 = (float*)p;   p += (size_t)NHEADS * VOCAB * 4;
  float* TW2 = (float*)p;   p += (size_t)NHEADS * VOCAB * 4;
  unsigned long long* nfm = (unsigned long long*)p;
  p += (size_t)BB * VOCAB * 32 * 8;                                      // 30 KB
  if ((size_t)(p - (char*)d_ws) > ws_size) return;

  // 0) mega-setup: adj pack + zeros + vocab masks + W_out transpose + TW
  setup_kernel<<<PACK_B + ZERO_B + NFM_B + TRAN_B + TW_B, 256, 0, stream>>>(
      adjs, padj, Wh1, node_feats, nfm, W_out, Wt_o, embed_table, W_heads,
      TWp);

  // 1) layer 1 via rank-15 structure: TW reduce, a-dots, popcount-P16, expand
  tw_reduce_kernel<<<12, 256, 0, stream>>>(TWp, TW);
  tw12_kernel<<<NHEADS * VOCAB, 256, 0, stream>>>(TW, a_heads, TW1, TW2);
  p16_kernel<<<16384 / 4, 256, 0, stream>>>(
      node_feats, (const unsigned*)padj, (const unsigned*)nfm, TW1, TW2, P16);
  hcat_expand<<<dim3(24, 128), 256, 0, stream>>>(TW, P16, hcat);

  // 2) output GAT layer (full-rank): proj2 -> Wh_t + Wh1/Wh2 atomics
  mfma_gemm<0><<<dim3(HID / 128, MTOT / 128, 1), 256, 0, stream>>>(
      hcat, Wt_o, NHEADS * HID, NHEADS * HID, NHEADS * HID, 0, 0,
      nullptr, Wh_t, a_out, Wh1, Wh2);
  attn_softmax_kernel<<<MTOT, 256, 0, stream>>>(Wh1, Wh2, padj, att2, out, 24);
  mfma_gemm<3><<<dim3(HID / 128, NN / 128, BB), 256, 0, stream>>>(
      att2, Wh_t, NN, NN, NN, (long)NN * NN, (long)HID * NN,
      out, nullptr, nullptr, nullptr, nullptr);
}

// Round 16
// 434.465 us; speedup vs baseline: 1.5995x; 1.2400x over previous
//
#include <hip/hip_runtime.h>
#include <math.h>

#define BB 8
#define NN 2048
#define HID 768
#define NHEADS 4
#define VOCAB 15
#define ALPHA 0.2f
#define NEGV -9e15f
#define MTOT (BB * NN)  // 16384

using short4v = __attribute__((ext_vector_type(4))) short;
using short8v = __attribute__((ext_vector_type(8))) short;
using f32x4 = __attribute__((ext_vector_type(4))) float;

__device__ __forceinline__ short f2bf(float f) {
  union { float f; unsigned u; } x;
  x.f = f;
  unsigned r = x.u + 0x7fffu + ((x.u >> 16) & 1u);
  return (short)(r >> 16);
}

__device__ __forceinline__ void cp16(const void* g, void* l) {
  __builtin_amdgcn_global_load_lds(
      (const __attribute__((address_space(1))) unsigned int*)g,
      (__attribute__((address_space(3))) unsigned int*)l, 16, 0, 0);
}

// pack 8 bytes' low nibbles (LE order) into 32 bits
__device__ __forceinline__ unsigned long long nibcompress(unsigned long long x) {
  x = (x | (x >> 4)) & 0x00FF00FF00FF00FFull;
  x = (x | (x >> 8)) & 0x0000FFFF0000FFFFull;
  x = (x | (x >> 16)) & 0x00000000FFFFFFFFull;
  return x;
}

// ---------------------------------------------------------------------------
// Mega-setup: [0,PACK_B) adjacency bit-pack, int4-vectorized (1024/block);
// [+ZERO_B) zero {Wh1,Wh2,TW1,TW2,pad}; [+NFM_B) per-batch vocab bitmasks;
// [+TRAN_B) W_out transpose; [+TW_B) TW partials (per-ky disjoint slots).
// ---------------------------------------------------------------------------
#define PACK_B 32768
#define ZERO_B 308
#define NFM_B 64
#define TRAN_B 2304  // 96 x 24 tiles of 32x32
#define TW_B 192     // 12 col-chunks x 16 k-chunks
__global__ __launch_bounds__(256) void setup_kernel(
    const int* __restrict__ adj, unsigned long long* __restrict__ packed,
    float* __restrict__ zbase, const int* __restrict__ nf,
    unsigned long long* __restrict__ nfm, const float* __restrict__ W_out,
    short* __restrict__ Wt_o, const float* __restrict__ table,
    const float* __restrict__ W_heads, float* __restrict__ TWp) {
  const int bid = blockIdx.x;
  const int tid = threadIdx.x;
  if (bid < PACK_B) {
    // 1024 adj values/block: each thread one int4, nibble -> LDS, 16 threads
    // assemble u64 words via nibble-compress.
    __shared__ unsigned long long nibq[32];
    long base = (long)bid * 1024;
    int4 a = *(const int4*)(adj + base + tid * 4);
    unsigned nib = (a.x > 0 ? 1u : 0u) | (a.y > 0 ? 2u : 0u) |
                   (a.z > 0 ? 4u : 0u) | (a.w > 0 ? 8u : 0u);
    ((unsigned char*)nibq)[tid] = (unsigned char)nib;
    __syncthreads();
    if (tid < 16) {
      unsigned long long lo = nibcompress(nibq[2 * tid]);
      unsigned long long hi = nibcompress(nibq[2 * tid + 1]);
      packed[(base >> 6) + tid] = lo | (hi << 32);
    }
  } else if (bid < PACK_B + ZERO_B) {
    zbase[(bid - PACK_B) * 256 + tid] = 0.f;
  } else if (bid < PACK_B + ZERO_B + NFM_B) {
    int r = bid - PACK_B - ZERO_B;  // 0..63
    int b = r >> 3, c = r & 7;
    int w = tid >> 6;
    int j = c * 256 + tid;
    int nfv = nf[b * NN + j];
#pragma unroll
    for (int v = 0; v < VOCAB; ++v) {
      unsigned long long m = __ballot(nfv == v);
      if ((tid & 63) == 0) nfm[((long)b * VOCAB + v) * 32 + c * 4 + w] = m;
    }
  } else if (bid < PACK_B + ZERO_B + NFM_B + TRAN_B) {
    // W_out transpose (3072x768 -> bf16 768x3072)
    __shared__ float t[32][33];
    int r2 = bid - PACK_B - ZERO_B - NFM_B;
    const int K = NHEADS * HID, N = HID;
    int k0 = (r2 % 96) * 32, n0 = (r2 / 96) * 32;
    int tx = tid & 31, ty = tid >> 5;
#pragma unroll
    for (int i = 0; i < 32; i += 8)
      t[ty + i][tx] = W_out[(long)(k0 + ty + i) * N + n0 + tx];
    __syncthreads();
#pragma unroll
    for (int i = 0; i < 32; i += 8)
      Wt_o[(long)(n0 + ty + i) * K + k0 + tx] = f2bf(t[tx][ty + i]);
  } else {
    // TW partial: col-chunk cx (256 cols), k-chunk ky (48 k) -> disjoint slot
    __shared__ float tbl[VOCAB][48];
    int r3 = bid - PACK_B - ZERO_B - NFM_B - TRAN_B;  // 0..191
    const int cx = r3 % 12, ky = r3 / 12;
    const int c = cx * 256 + tid;
    const int h = (cx * 256) / HID;
    const int n = c - h * HID;
    const int k0 = ky * 48;
    for (int idx = tid; idx < VOCAB * 48; idx += 256)
      tbl[idx / 48][idx % 48] = table[(idx / 48) * HID + k0 + idx % 48];
    __syncthreads();
    float acc[VOCAB];
#pragma unroll
    for (int v = 0; v < VOCAB; ++v) acc[v] = 0.f;
    const float* wp = W_heads + (long)h * HID * HID + (long)k0 * HID + n;
#pragma unroll 8
    for (int kk = 0; kk < 48; ++kk) {
      float w = wp[(long)kk * HID];
#pragma unroll
      for (int v = 0; v < VOCAB; ++v) acc[v] = fmaf(tbl[v][kk], w, acc[v]);
    }
#pragma unroll
    for (int v = 0; v < VOCAB; ++v)
      TWp[((long)ky * VOCAB + v) * (NHEADS * HID) + c] = acc[v];
  }
}

// ---------------------------------------------------------------------------
// Fused: reduce 16 TW partials -> TW, and accumulate a-dot partials into
// TW1/TW2 (zeroed by setup) via per-block reduce + atomicAdd. grid 12.
// ---------------------------------------------------------------------------
__global__ __launch_bounds__(256) void tw_finish_kernel(
    const float* __restrict__ TWp, float* __restrict__ TW,
    const float* __restrict__ a_heads, float* __restrict__ TW1,
    float* __restrict__ TW2) {
  const int tid = threadIdx.x;
  const int c = blockIdx.x * 256 + tid;  // 0..3071
  const int h = (blockIdx.x * 256) / HID;  // uniform per block
  const int n = c - h * HID;
  const float a1 = a_heads[h * 2 * HID + n];
  const float a2 = a_heads[h * 2 * HID + HID + n];
  const int lane = tid & 63;
  const int wv = tid >> 6;
  __shared__ float red[4][2 * VOCAB];

  float s1[VOCAB], s2[VOCAB];
#pragma unroll
  for (int v = 0; v < VOCAB; ++v) {
    float s = 0.f;
#pragma unroll
    for (int ky = 0; ky < 16; ++ky)
      s += TWp[((long)ky * VOCAB + v) * (NHEADS * HID) + c];
    TW[v * (NHEADS * HID) + c] = s;
    s1[v] = s * a1;
    s2[v] = s * a2;
  }
#pragma unroll
  for (int off = 1; off < 64; off <<= 1)
#pragma unroll
    for (int v = 0; v < VOCAB; ++v) {
      s1[v] += __shfl_xor(s1[v], off);
      s2[v] += __shfl_xor(s2[v], off);
    }
  if (lane == 0) {
#pragma unroll
    for (int v = 0; v < VOCAB; ++v) {
      red[wv][v] = s1[v];
      red[wv][VOCAB + v] = s2[v];
    }
  }
  __syncthreads();
  if (tid < 2 * VOCAB) {
    float s = red[0][tid] + red[1][tid] + red[2][tid] + red[3][tid];
    float* dst = (tid < VOCAB) ? (TW1 + h * VOCAB + tid)
                               : (TW2 + h * VOCAB + tid - VOCAB);
    atomicAdd(dst, s);
  }
}

// ---------------------------------------------------------------------------
// P16 via popcount: one wave per row; 15-value softmax for all 4 heads.
// ---------------------------------------------------------------------------
__global__ __launch_bounds__(256) void p16_kernel(
    const int* __restrict__ nf, const unsigned* __restrict__ padj32,
    const unsigned* __restrict__ nfm32, const float* __restrict__ TW1,
    const float* __restrict__ TW2, float* __restrict__ P16) {
  const int t = threadIdx.x;
  const int wv = t >> 6;
  const int lane = t & 63;
  const int rowm = blockIdx.x * 4 + wv;
  const int b = rowm >> 11;
  __shared__ float cnts[4][16];

  unsigned a = padj32[(long)rowm * 64 + lane];
  const unsigned* nb = nfm32 + (long)b * VOCAB * 64 + lane;
  int cnt[VOCAB];
#pragma unroll
  for (int v = 0; v < VOCAB; ++v) cnt[v] = __popc(a & nb[v * 64]);
#pragma unroll
  for (int off = 1; off < 64; off <<= 1)
#pragma unroll
    for (int v = 0; v < VOCAB; ++v) cnt[v] += __shfl_xor(cnt[v], off);
  int cntsum = 0;
#pragma unroll
  for (int v = 0; v < VOCAB; ++v) cntsum += cnt[v];
  const bool use_full = (cntsum == 0);  // wave-uniform
  if (use_full) {
#pragma unroll
    for (int v = 0; v < VOCAB; ++v) cnt[v] = __popc(nb[v * 64]);
#pragma unroll
    for (int off = 1; off < 64; off <<= 1)
#pragma unroll
      for (int v = 0; v < VOCAB; ++v) cnt[v] += __shfl_xor(cnt[v], off);
  }
  if (lane < 16) cnts[wv][lane] = (lane < VOCAB) ? (float)cnt[lane] : 0.f;
  __syncthreads();

  const int h = lane >> 4;
  const int v = lane & 15;
  const int nfi = nf[b * NN + (rowm & 2047)];
  float cvf = cnts[wv][v];
  bool valid = (v < VOCAB) && (cvf > 0.f);
  float logit = 0.f;
  if (!use_full) {
    float s = TW1[h * VOCAB + nfi] + ((v < VOCAB) ? TW2[h * VOCAB + v] : 0.f);
    logit = s > 0.f ? s : ALPHA * s;
  }
  float mv = valid ? logit : -INFINITY;
#pragma unroll
  for (int off = 1; off < 16; off <<= 1) mv = fmaxf(mv, __shfl_xor(mv, off));
  float pv = valid ? cvf * __expf(logit - mv) : 0.f;
  float sum = pv;
#pragma unroll
  for (int off = 1; off < 16; off <<= 1) sum += __shfl_xor(sum, off);
  if (v < VOCAB) P16[((long)h * 16384 + rowm) * 16 + v] = pv / sum;
}

// ---------------------------------------------------------------------------
// hcat[r][h*HID+colh] = ELU( sum_v P16[h][r][v] * TW[v][h*HID+colh] ) -> bf16
// Round-13 layout: 4 cols x 16 rows per thread, short4v stores.
// ---------------------------------------------------------------------------
__global__ __launch_bounds__(256) void hcat_expand(
    const float* __restrict__ TW, const float* __restrict__ P16,
    short* __restrict__ hcat) {
  __shared__ float twl[VOCAB * 128];
  __shared__ float pl[128 * 16];
  const int c0 = blockIdx.x * 128;
  const int r0 = blockIdx.y * 128;
  const int h = c0 / HID;
  const int t = threadIdx.x;
  for (int idx = t; idx < VOCAB * 128; idx += 256)
    twl[idx] = TW[(idx / 128) * (NHEADS * HID) + c0 + (idx & 127)];
  for (int idx = t; idx < 128 * 16; idx += 256)
    pl[idx] = P16[((long)h * 16384 + r0 + (idx >> 4)) * 16 + (idx & 15)];
  __syncthreads();
  const int clb = (t & 31) * 4;
  const int rlb = (t >> 5) * 16;
#pragma unroll 4
  for (int rr = 0; rr < 16; ++rr) {
    int rl = rlb + rr;
    short4v o;
#pragma unroll
    for (int cc = 0; cc < 4; ++cc) {
      float s = 0.f;
#pragma unroll
      for (int vv = 0; vv < VOCAB; ++vv)
        s = fmaf(pl[rl * 16 + vv], twl[vv * 128 + clb + cc], s);
      s = s > 0.f ? s : (__expf(s) - 1.f);
      o[cc] = f2bf(s);
    }
    *(short4v*)(hcat + (long)(r0 + rl) * (NHEADS * HID) + c0 + clb) = o;
  }
}

// ---------------------------------------------------------------------------
// bf16 MFMA GEMM, 128x128 tile, BK=32, XCD swizzle, LDS-repacked epilogues.
// MODE 0: Ct bf16 [bb][colh][row] via LDS + fused a-dot atomics (layer 2).
// MODE 3: fused ELU + mean-pool: atomicAdd Cf[z*HID + col].
// ---------------------------------------------------------------------------
template <int MODE>
__global__ __launch_bounds__(256, 4) void mfma_gemm(
    const short* __restrict__ A, const short* __restrict__ B,
    int K, int lda, int ldb, long sA, long sB,
    float* __restrict__ Cf, short* __restrict__ Ct,
    const float* __restrict__ a_vec, float* __restrict__ Wh1g,
    float* __restrict__ Wh2g) {
  __shared__ short smem[8704];  // As 4096 + Bs 4096; reused as ctile
  short* As = smem;
  short* Bs = smem + 4096;

  const int gx = gridDim.x, gy = gridDim.y;
  int lin = blockIdx.x + gx * (blockIdx.y + gy * blockIdx.z);
  const int per = (gx * gy * gridDim.z) >> 3;
  int work = (lin & 7) * per + (lin >> 3);
  const int bx = work % gx;
  int tmp = work / gx;
  const int by = tmp % gy;
  const int z = tmp / gy;

  A += (long)z * sA;
  B += (long)z * sB;

  const int tid = threadIdx.x;
  const int m0 = by * 128;
  const int n0 = bx * 128;

  const int lane = tid & 63;
  const int wid = tid >> 6;
  const int wm = (wid & 1) * 64;
  const int wn = (wid >> 1) * 64;
  const int l15 = lane & 15;
  const int quad = lane >> 4;
  const int cp = quad ^ ((l15 >> 1) & 3);

  f32x4 acc[4][4];
#pragma unroll
  for (int i = 0; i < 4; ++i)
#pragma unroll
    for (int j = 0; j < 4; ++j) acc[i][j] = (f32x4){0.f, 0.f, 0.f, 0.f};

  for (int k0 = 0; k0 < K; k0 += 32) {
#pragma unroll
    for (int it = 0; it < 2; ++it) {
      int lin2 = it * 256 + tid;
      int r = lin2 >> 2;
      int p = lin2 & 3;
      int kc = p ^ ((r >> 1) & 3);
      cp16(A + (long)(m0 + r) * lda + k0 + kc * 8, &As[lin2 * 8]);
    }
#pragma unroll
    for (int it = 0; it < 2; ++it) {
      int lin2 = it * 256 + tid;
      int r = lin2 >> 2;
      int p = lin2 & 3;
      int kc = p ^ ((r >> 1) & 3);
      cp16(B + (long)(n0 + r) * ldb + k0 + kc * 8, &Bs[lin2 * 8]);
    }
    __syncthreads();

    short8v af[4], bfr[4];
#pragma unroll
    for (int i = 0; i < 4; ++i)
      af[i] = *(const short8v*)(As + (wm + i * 16 + l15) * 32 + cp * 8);
#pragma unroll
    for (int j = 0; j < 4; ++j)
      bfr[j] = *(const short8v*)(Bs + (wn + j * 16 + l15) * 32 + cp * 8);
#pragma unroll
    for (int i = 0; i < 4; ++i)
#pragma unroll
      for (int j = 0; j < 4; ++j)
        acc[i][j] = __builtin_amdgcn_mfma_f32_16x16x32_bf16(af[i], bfr[j],
                                                            acc[i][j], 0, 0, 0);
    __syncthreads();
  }

  // ---- epilogues (C/D layout: col=lane&15 group, row=quad*4+reg) ----
  if constexpr (MODE == 3) {
#pragma unroll
    for (int j = 0; j < 4; ++j) {
      int col = n0 + wn + j * 16 + l15;
      float s = 0.f;
#pragma unroll
      for (int i = 0; i < 4; ++i)
#pragma unroll
        for (int reg = 0; reg < 4; ++reg) {
          float v = acc[i][j][reg];
          s += v > 0.f ? v : (__expf(v) - 1.f);
        }
      s += __shfl_xor(s, 16);
      s += __shfl_xor(s, 32);
      if (quad == 0) atomicAdd(Cf + (long)z * HID + col, s * (1.0f / NN));
    }
  } else {  // MODE 0: a-dot + transposed Ct via LDS [col][row] (stride 136)
    float a1v[4], a2v[4];
#pragma unroll
    for (int j = 0; j < 4; ++j) {
      int colh = n0 + wn + j * 16 + l15;  // single-head output (N=768)
      a1v[j] = a_vec[colh];
      a2v[j] = a_vec[HID + colh];
    }
#pragma unroll
    for (int i = 0; i < 4; ++i) {
      int rb = m0 + wm + i * 16 + quad * 4;
#pragma unroll
      for (int reg = 0; reg < 4; ++reg) {
        float s1 = 0.f, s2 = 0.f;
#pragma unroll
        for (int j = 0; j < 4; ++j) {
          s1 = fmaf(acc[i][j][reg], a1v[j], s1);
          s2 = fmaf(acc[i][j][reg], a2v[j], s2);
        }
#pragma unroll
        for (int off = 1; off < 16; off <<= 1) {
          s1 += __shfl_xor(s1, off);
          s2 += __shfl_xor(s2, off);
        }
        if (l15 == 0) {
          atomicAdd(Wh1g + rb + reg, s1);
          atomicAdd(Wh2g + rb + reg, s2);
        }
      }
    }
    const int bb = m0 >> 11;
    const int ml0 = m0 & 2047;
#pragma unroll
    for (int p = 0; p < 2; ++p) {
      if (wn == p * 64) {
#pragma unroll
        for (int j = 0; j < 4; ++j) {
          int col_l = j * 16 + l15;
#pragma unroll
          for (int i = 0; i < 4; ++i) {
            int row_l = wm + i * 16 + quad * 4;
            short4v pk;
#pragma unroll
            for (int reg = 0; reg < 4; ++reg) pk[reg] = f2bf(acc[i][j][reg]);
            *(short4v*)(smem + col_l * 136 + row_l) = pk;
          }
        }
      }
      __syncthreads();
#pragma unroll
      for (int it = 0; it < 4; ++it) {
        int idx = it * 256 + tid;
        int col_l = idx >> 4;
        int ch = idx & 15;
        short8v ld = *(const short8v*)(smem + col_l * 136 + ch * 8);
        int colh = n0 + p * 64 + col_l;
        *(short8v*)(Ct + ((long)bb * HID + colh) * NN + ml0 + ch * 8) = ld;
      }
      __syncthreads();
    }
  }
}

// ---------------------------------------------------------------------------
// Layer-2 row softmax (materializing, bf16 att). grid 16384. Blocks [0,zn)
// also zero zA (final output accumulator; write-disjoint from reads).
// ---------------------------------------------------------------------------
__global__ __launch_bounds__(256) void attn_softmax_kernel(
    const float* __restrict__ Wh1, const float* __restrict__ Wh2,
    const unsigned long long* __restrict__ packed, short* __restrict__ att,
    float* __restrict__ zA, int zn) {
  int row = blockIdx.x;
  if (row < zn) zA[row * 256 + threadIdx.x] = 0.f;
  int b = row >> 11;
  const unsigned char* bits = (const unsigned char*)(packed + (long)row * 32);
  const float* wh2b = Wh2 + b * NN;
  const int t = threadIdx.x;
  const int lane = t & 63;
  const int wv = t >> 6;

  unsigned m8 = bits[t];
  float wh1 = Wh1[row];
  float4 wa = ((const float4*)(wh2b + t * 8))[0];
  float4 wb = ((const float4*)(wh2b + t * 8))[1];
  float v[8] = {wa.x, wa.y, wa.z, wa.w, wb.x, wb.y, wb.z, wb.w};

  float lmax = -INFINITY;
#pragma unroll
  for (int k = 0; k < 8; ++k) {
    float s = wh1 + v[k];
    s = s > 0.f ? s : ALPHA * s;
    s = ((m8 >> k) & 1u) ? s : NEGV;
    v[k] = s;
    lmax = fmaxf(lmax, s);
  }

  __shared__ float redm[4], reds[4];
#pragma unroll
  for (int off = 32; off > 0; off >>= 1) lmax = fmaxf(lmax, __shfl_xor(lmax, off));
  if (lane == 0) redm[wv] = lmax;
  __syncthreads();
  float m = fmaxf(fmaxf(redm[0], redm[1]), fmaxf(redm[2], redm[3]));

  float lsum = 0.f;
#pragma unroll
  for (int k = 0; k < 8; ++k) {
    float p = __expf(v[k] - m);
    v[k] = p;
    lsum += p;
  }
#pragma unroll
  for (int off = 32; off > 0; off >>= 1) lsum += __shfl_xor(lsum, off);
  if (lane == 0) reds[wv] = lsum;
  __syncthreads();
  float inv = 1.f / (reds[0] + reds[1] + reds[2] + reds[3]);

  short8v o;
#pragma unroll
  for (int k = 0; k < 8; ++k) o[k] = f2bf(v[k] * inv);
  *(short8v*)(att + (long)row * NN + t * 8) = o;
}

// ---------------------------------------------------------------------------
extern "C" void kernel_launch(void* const* d_in, const int* in_sizes, int n_in,
                              void* d_out, int out_size, void* d_ws,
                              size_t ws_size, hipStream_t stream) {
  const int* node_feats = (const int*)d_in[0];
  const int* adjs = (const int*)d_in[1];
  const float* embed_table = (const float*)d_in[2];
  const float* W_heads = (const float*)d_in[3];
  const float* a_heads = (const float*)d_in[4];
  const float* W_out = (const float*)d_in[5];
  const float* a_out = (const float*)d_in[6];
  float* out = (float*)d_out;

  // workspace layout (~215 MB)
  char* p = (char*)d_ws;
  short* Wt_o = (short*)p;  p += (size_t)HID * (NHEADS * HID) * 2;       // 4.7 MB
  short* Wh_t = (short*)p;  p += (size_t)BB * HID * NN * 2;              // 25 MB
  short* att2 = (short*)p;  p += (size_t)BB * NN * NN * 2;               // 67 MB
  short* hcat = (short*)p;  p += (size_t)MTOT * NHEADS * HID * 2;        // 100 MB
  unsigned long long* padj = (unsigned long long*)p;
  p += (size_t)BB * NN * NN / 8;                                         // 4.2 MB
  float* P16 = (float*)p;   p += (size_t)NHEADS * 16384 * 16 * 4;        // 4 MB
  // zero region (ZERO_B*256 floats): Wh1, Wh2, TW1, TW2, pad
  float* Wh1 = (float*)p;   p += (size_t)16384 * 4;
  float* Wh2 = (float*)p;   p += (size_t)16384 * 4;
  float* TW1 = (float*)p;   p += (size_t)64 * 4;
  float* TW2 = (float*)p;   p += (size_t)64 * 4;
  p += (size_t)(ZERO_B * 256 - 2 * 16384 - 128) * 4;  // pad (zeroed)
  float* TWp = (float*)p;   p += (size_t)16 * VOCAB * NHEADS * HID * 4;  // 2.9 MB
  float* TW = (float*)p;    p += (size_t)VOCAB * NHEADS * HID * 4;
  unsigned long long* nfm = (unsigned long long*)p;
  p += (size_t)BB * VOCAB * 32 * 8;                                      // 30 KB
  if ((size_t)(p - (char*)d_ws) > ws_size) return;

  // 0) mega-setup: vectorized adj pack + zeros + vocab masks + transpose + TW
  setup_kernel<<<PACK_B + ZERO_B + NFM_B + TRAN_B + TW_B, 256, 0, stream>>>(
      adjs, padj, Wh1, node_feats, nfm, W_out, Wt_o, embed_table, W_heads,
      TWp);

  // 1) layer 1: TW reduce + a-dots (fused), popcount-P16, expand
  tw_finish_kernel<<<12, 256, 0, stream>>>(TWp, TW, a_heads, TW1, TW2);
  p16_kernel<<<16384 / 4, 256, 0, stream>>>(
      node_feats, (const unsigned*)padj, (const unsigned*)nfm, TW1, TW2, P16);
  hcat_expand<<<dim3(24, 128), 256, 0, stream>>>(TW, P16, hcat);

  // 2) output GAT layer (full-rank): proj2 -> Wh_t + Wh1/Wh2 atomics
  mfma_gemm<0><<<dim3(HID / 128, MTOT / 128, 1), 256, 0, stream>>>(
      hcat, Wt_o, NHEADS * HID, NHEADS * HID, NHEADS * HID, 0, 0,
      nullptr, Wh_t, a_out, Wh1, Wh2);
  attn_softmax_kernel<<<MTOT, 256, 0, stream>>>(Wh1, Wh2, padj, att2, out, 24);
  mfma_gemm<3><<<dim3(HID / 128, NN / 128, BB), 256, 0, stream>>>(
      att2, Wh_t, NN, NN, NN, (long)NN * NN, (long)HID * NN,
      out, nullptr, nullptr, nullptr, nullptr);
}